// Round 7
// baseline (265.121 us; speedup 1.0000x reference)
//
#include <hip/hip_runtime.h>
#include <math.h>

// ---------- problem constants ----------
#define BB 4
#define SS 4096
#define EE 1024
#define HH 16
#define DD 64
#define MM (BB*SS)          // 16384 rows

typedef _Float16 f16x8 __attribute__((ext_vector_type(8)));
typedef _Float16 f16x4 __attribute__((ext_vector_type(4)));
typedef float    f32x4 __attribute__((ext_vector_type(4)));

typedef __attribute__((address_space(3))) void lds_void;
typedef __attribute__((address_space(1))) void gm_void;

__device__ __forceinline__ void gload16(const void* g, void* l) {
  // async global->LDS, 16B per lane; LDS dest is wave-uniform base + lane*16
  __builtin_amdgcn_global_load_lds((gm_void*)g, (lds_void*)l, 16, 0, 0);
}

// ---------- fused conversion kernel (x -> f16, 4 weight mats -> f16) ----------
__global__ __launch_bounds__(256) void conv_all_kernel(const float* __restrict__ x,
                                                       const float* __restrict__ Wq,
                                                       const float* __restrict__ Wk,
                                                       const float* __restrict__ Wv,
                                                       const float* __restrict__ Wo,
                                                       _Float16* __restrict__ xh,
                                                       _Float16* __restrict__ wqkv,
                                                       _Float16* __restrict__ woh) {
  const int nx4 = (MM * EE) / 4;       // 4,194,304
  const int per = (EE * EE) / 4;       // 262,144
  const int ntot = nx4 + 4 * per;      // 5,242,880
  int i = blockIdx.x * blockDim.x + threadIdx.x;
  int stride = gridDim.x * blockDim.x;
  for (; i < ntot; i += stride) {
    const float* src;
    _Float16* dst;
    int off;
    if (i < nx4) {
      src = x; dst = xh; off = i;
    } else {
      int j = i - nx4;
      int seg = j / per; off = j - seg * per;
      src = (seg == 0) ? Wq : (seg == 1) ? Wk : (seg == 2) ? Wv : Wo;
      dst = (seg < 3) ? (wqkv + (size_t)seg * EE * EE) : woh;
    }
    f32x4 v = *(const f32x4*)&src[(size_t)off * 4];
    f16x4 h;
    h[0] = (_Float16)v[0]; h[1] = (_Float16)v[1];
    h[2] = (_Float16)v[2]; h[3] = (_Float16)v[3];
    *(f16x4*)&dst[(size_t)off * 4] = h;
  }
}

// ---------- 256x128 fp16 MFMA GEMM v6: BK=32, ring-3 LDS (72KB), 2 blocks/CU ----------
// C[m][n] = sum_k A[m][k]*B[n][k], K = 1024 -> 32 K-tiles of BK=32.
// 256 threads = 4 waves (2M x 2N); per-wave output 128x64; acc[8][4] f32x4.
// LDS: A 3 x 16KB + B 3 x 8KB = 72KB -> 2 blocks/CU.
// v6 vs v5: counted vmcnt(6) instead of vmcnt(0) per tile. Stage(t+2) issued at
// tile t; vmcnt(6) at tile t retires stage(t+1) (issued one full window earlier)
// while stage(t+2) stays in flight ACROSS the barrier -> the gload_lds DMA's
// L2-latency + LDS-port-queue time never gates the window. Invariant at tile-t
// entry: outstanding = stage(t+1) [6 loads]. WAR: stage(t+2) hits buf (t-1)%3,
// whose 12 reads retired (lgkm, in-order) before barrier(t-1). 2 independent
// blocks/CU additionally overlap read-burst vs MFMA across barriers (m114).

#define SCB() __builtin_amdgcn_sched_barrier(0)
#define VMW6 asm volatile("s_waitcnt vmcnt(6)" ::: "memory")
#define VMW0 asm volatile("s_waitcnt vmcnt(0)" ::: "memory")
#define BARR do { SCB(); __builtin_amdgcn_s_barrier(); SCB(); } while (0)
#define NOP_ do {} while (0)

// stage 16 rows (4 lanes/row x 16B) of K-tile t into ring buf bf;
// dest linear, src inverse-swizzled
#define STAGE_A(t, g, bf) gload16(Ag + ((size_t)(g) << 15) + (size_t)(t) * 64, \
                                  LdsA + (bf) * 16384 + (((wv << 2) + (g)) << 10))
#define STAGE_B(t, g, bf) gload16(Bg + ((size_t)(g) << 15) + (size_t)(t) * 64, \
                                  LdsB + (bf) * 8192 + (((wv << 1) + (g)) << 10))
#define STG6(t, bf) do { STAGE_A(t, 0, bf); STAGE_A(t, 1, bf); STAGE_A(t, 2, bf); \
                         STAGE_B(t, 0, bf); STAGE_B(t, 1, bf); STAGE_A(t, 3, bf); } while (0)

// swizzled fragment reads (row stride 64B; slot XOR'd by (row>>1)&3, in lof)
#define RD_A(bf, mf) (*(const f16x8*)(LdsA + (bf) * 16384 + ((wr8 + (mf)) << 10) + lof))
#define RD_B(bf, nf) (*(const f16x8*)(LdsB + (bf) * 8192 + ((wc4 + (nf)) << 10) + lof))

#define TILE_(bf, STG, VW, BAR) do {                                         \
    STG;                                                                     \
    f16x8 fB0 = RD_B(bf, 0), fB1 = RD_B(bf, 1);                              \
    f16x8 fB2 = RD_B(bf, 2), fB3 = RD_B(bf, 3);                              \
    __builtin_amdgcn_s_setprio(1);                                           \
    _Pragma("unroll") for (int mf = 0; mf < 8; mf++) {                       \
      if (mf == 4) SCB();                                                    \
      f16x8 fA = RD_A(bf, mf);                                               \
      acc[mf][0] = __builtin_amdgcn_mfma_f32_16x16x32_f16(fA, fB0, acc[mf][0], 0, 0, 0); \
      acc[mf][1] = __builtin_amdgcn_mfma_f32_16x16x32_f16(fA, fB1, acc[mf][1], 0, 0, 0); \
      acc[mf][2] = __builtin_amdgcn_mfma_f32_16x16x32_f16(fA, fB2, acc[mf][2], 0, 0, 0); \
      acc[mf][3] = __builtin_amdgcn_mfma_f32_16x16x32_f16(fA, fB3, acc[mf][3], 0, 0, 0); \
    }                                                                        \
    __builtin_amdgcn_s_setprio(0);                                           \
    VW; BAR;                                                                 \
  } while (0)

template <int EPI>
__global__ __launch_bounds__(256, 2) void gemm256(const _Float16* __restrict__ A,
                                                  const _Float16* __restrict__ Bw,
                                                  const float* __restrict__ bias0,
                                                  const float* __restrict__ bias1,
                                                  const float* __restrict__ bias2,
                                                  _Float16* __restrict__ O0,
                                                  _Float16* __restrict__ O1,
                                                  _Float16* __restrict__ O2,
                                                  float* __restrict__ OF) {
  __shared__ __align__(16) char lds[73728];
  char* LdsA = lds;            // 3 ring bufs x 16KB
  char* LdsB = lds + 49152;    // 3 ring bufs x 8KB

  const int tid  = threadIdx.x;
  const int lane = tid & 63;
  const int wv   = tid >> 6;           // 0..3
  const int wr   = wv >> 1;            // 0..1 (row half: 128 rows)
  const int wc   = wv & 1;             // 0..1 (col half: 64 cols)
  const int wr8  = wr << 3;
  const int wc4  = wc << 2;

  // T1: bijective XCD swizzle (gridDim.x % 8 == 0 for both instantiations)
  constexpr int NXT = (EPI == 0) ? 24 : 8;   // N / 128
  const int q = (int)gridDim.x >> 3;
  const int bid = (int)blockIdx.x;
  const int sid = (bid & 7) * q + (bid >> 3);
  const int mbase = (sid / NXT) << 8;
  const int nbase = (sid % NXT) << 7;

  // read offset: row=(lane&15), slot=(lane>>4) XOR ((row>>1)&3); 16B slots
  const int lof = ((lane & 15) << 6) + (((lane >> 4) ^ ((lane >> 1) & 3)) << 4);
  // stage source per-lane offset: row=(lane>>2), stored slot p=(lane&3) holds
  // global slot p ^ ((row>>1)&3) = (lane&3) ^ ((lane>>3)&3)
  const int plane = ((lane >> 2) << 11) + (((lane & 3) ^ ((lane >> 3) & 3)) << 4);

  // wave wv stages A rows [wv*64 + g*16) and B rows [wv*32 + g*16)
  const char* Ag = (const char*)A + ((size_t)(mbase + (wv << 6)) << 11) + plane;
  const char* Bg = (const char*)Bw + ((size_t)(nbase + (wv << 5)) << 11) + plane;

  f32x4 acc[8][4] = {};

  // prologue: stage tiles 0,1; vmcnt(6) retires tile 0 (tile 1 stays in flight)
  STG6(0, 0); STG6(1, 1);
  VMW6; BARR;

#pragma unroll 1
  for (int i = 0; i < 10; ++i) {       // tiles 0..29
    const int t = i * 3;
    TILE_(0, STG6(t + 2, 2), VMW6, BARR);
    TILE_(1, STG6(t + 3, 0), VMW6, BARR);
    TILE_(2, STG6(t + 4, 1), VMW6, BARR);
  }
  // tail: tiles 30 (buf 0), 31 (buf 1); drain remaining stage(31) once
  TILE_(0, NOP_, VMW0, BARR);
  TILE_(1, NOP_, NOP_, NOP_);

  // epilogue: C/D layout col = lane&15, row = (lane>>4)*4 + j
  const int rl = (lane >> 4) << 2;
  const int cl = lane & 15;
  const int rb = mbase + (wr << 7);    // wave's 128-row block
  if (EPI == 0) {
    const int which = nbase >> 10;     // 0:Q 1:K 2:V (128-tile never straddles)
    const float* bias = (which == 0) ? bias0 : (which == 1) ? bias1 : bias2;
    _Float16* O = (which == 0) ? O0 : (which == 1) ? O1 : O2;
    const int cb = (nbase & 1023) + (wc << 6);
#pragma unroll
    for (int mf = 0; mf < 8; mf++) {
      const int gm = rb + (mf << 4) + rl;
#pragma unroll
      for (int nf = 0; nf < 4; nf++) {
        const int gc = cb + (nf << 4) + cl;
        const float bz = bias[gc];
#pragma unroll
        for (int j = 0; j < 4; j++) {
          float v = acc[mf][nf][j] + bz;
          if (which < 2) v = (v > 0.f) ? (v + 1.f) : expf(v);  // elu(v)+1
          O[(size_t)(gm + j) * EE + gc] = (_Float16)v;
        }
      }
    }
  } else {
    const int cb = nbase + (wc << 6);
#pragma unroll
    for (int mf = 0; mf < 8; mf++) {
      const int gm = rb + (mf << 4) + rl;
#pragma unroll
      for (int nf = 0; nf < 4; nf++) {
        const int gc = cb + (nf << 4) + cl;
        const float bz = bias0[gc];
#pragma unroll
        for (int j = 0; j < 4; j++)
          OF[(size_t)(gm + j) * EE + gc] = acc[mf][nf][j] + bz;
      }
    }
  }
}

#undef TILE_
#undef RD_A
#undef RD_B
#undef STG6
#undef STAGE_A
#undef STAGE_B

// ---------- stage 2: partial KV (K^T V) and partial K_sum, per (bh, s-chunk) ----------
__global__ __launch_bounds__(256) void kv_partial_kernel(const _Float16* __restrict__ Kh,
                                                         const _Float16* __restrict__ Vh,
                                                         float* __restrict__ kvpart,
                                                         float* __restrict__ ksump) {
  __shared__ __align__(16) _Float16 Ks[64 * 64];
  __shared__ __align__(16) _Float16 Vs[64 * 64];
  const int tid = threadIdx.x;
  const int wv = tid >> 6;
  const int bh = blockIdx.x;        // b*16 + h
  const int chunk = blockIdx.y;     // 16 chunks of 256 rows
  const int b = bh >> 4, h = bh & 15;
  const int td = tid >> 4, te = tid & 15;
  const int d0 = td * 4, e0 = te * 4;

  float kv[4][4] = {};
  float ks4[4] = {0.f, 0.f, 0.f, 0.f};

  for (int sub = 0; sub < 4; sub++) {
    const int s0 = chunk * 256 + sub * 64;
    __syncthreads();
    {
      const int g0 = tid, g1 = tid + 256;
      gload16((const char*)Kh + ((size_t)(b * SS + s0 + (g0 >> 3)) * EE + h * DD) * 2 + (g0 & 7) * 16,
              (char*)Ks + wv * 1024);
      gload16((const char*)Kh + ((size_t)(b * SS + s0 + (g1 >> 3)) * EE + h * DD) * 2 + (g1 & 7) * 16,
              (char*)Ks + 4096 + wv * 1024);
      gload16((const char*)Vh + ((size_t)(b * SS + s0 + (g0 >> 3)) * EE + h * DD) * 2 + (g0 & 7) * 16,
              (char*)Vs + wv * 1024);
      gload16((const char*)Vh + ((size_t)(b * SS + s0 + (g1 >> 3)) * EE + h * DD) * 2 + (g1 & 7) * 16,
              (char*)Vs + 4096 + wv * 1024);
    }
    __syncthreads();
#pragma unroll 8
    for (int s = 0; s < 64; s++) {
      f16x4 kk = *(const f16x4*)&Ks[s * 64 + d0];
      f16x4 vv = *(const f16x4*)&Vs[s * 64 + e0];
      float kf[4], vf[4];
#pragma unroll
      for (int i = 0; i < 4; i++) { kf[i] = (float)kk[i]; vf[i] = (float)vv[i]; }
#pragma unroll
      for (int i = 0; i < 4; i++)
#pragma unroll
        for (int j = 0; j < 4; j++) kv[i][j] += kf[i] * vf[j];
      if (te == 0) {
#pragma unroll
        for (int i = 0; i < 4; i++) ks4[i] += kf[i];
      }
    }
  }
  const size_t base = ((size_t)chunk * 64 + bh) * 4096;
#pragma unroll
  for (int i = 0; i < 4; i++)
#pragma unroll
    for (int j = 0; j < 4; j++) kvpart[base + (size_t)(d0 + i) * 64 + e0 + j] = kv[i][j];
  if (te == 0) {
#pragma unroll
    for (int i = 0; i < 4; i++) ksump[((size_t)chunk * 64 + bh) * 64 + d0 + i] = ks4[i];
  }
}

// ---------- stage 2b: reduce partials -> KV^T (fp16, [bh][e][d]) and K_sum (f32) ----------
__global__ __launch_bounds__(256) void kv_reduce_kernel(const float* __restrict__ kvpart,
                                                        const float* __restrict__ ksump,
                                                        _Float16* __restrict__ kvt,
                                                        float* __restrict__ ksum) {
  const int idx = blockIdx.x * 256 + threadIdx.x;
  if (blockIdx.x < 1024) {
    const int bh = idx >> 12;
    const int rem = idx & 4095;     // d*64 + e
    float s = 0.f;
#pragma unroll
    for (int c = 0; c < 16; c++) s += kvpart[((size_t)c * 64 + bh) * 4096 + rem];
    const int d = rem >> 6, e = rem & 63;
    kvt[(size_t)bh * 4096 + e * 64 + d] = (_Float16)s;
  } else {
    const int i2 = idx - 1024 * 256;  // 0..4095
    const int bh = i2 >> 6, d = i2 & 63;
    float s = 0.f;
#pragma unroll
    for (int c = 0; c < 16; c++) s += ksump[((size_t)c * 64 + bh) * 64 + d];
    ksum[i2] = s;
  }
}

// ---------- stage 3: attn[m][h*64+e] = Z * sum_d Q[m][d] * KV[d][e] ----------
__global__ __launch_bounds__(256) void attn_kernel(const _Float16* __restrict__ Qh,
                                                   const _Float16* __restrict__ kvt,
                                                   const float* __restrict__ ksum,
                                                   _Float16* __restrict__ attn) {
  __shared__ __align__(16) _Float16 Qs[64 * 64];
  __shared__ __align__(16) _Float16 KVs[64 * 64];
  __shared__ float ks_lds[64];
  __shared__ float dpart[4][64];
  __shared__ float zr[64];
  const int tid = threadIdx.x;
  const int lane = tid & 63;
  const int wv = tid >> 6;
  const int stile = blockIdx.x;     // 64 tiles of 64 rows
  const int bh = blockIdx.y;
  const int b = bh >> 4, h = bh & 15;
  const int m0 = b * SS + stile * 64;

  {
    const int g0 = tid, g1 = tid + 256;
    gload16((const char*)Qh + ((size_t)(m0 + (g0 >> 3)) * EE + h * DD) * 2 + (g0 & 7) * 16,
            (char*)Qs + wv * 1024);
    gload16((const char*)Qh + ((size_t)(m0 + (g1 >> 3)) * EE + h * DD) * 2 + (g1 & 7) * 16,
            (char*)Qs + 4096 + wv * 1024);
    gload16((const char*)kvt + (size_t)bh * 8192 + (size_t)g0 * 16, (char*)KVs + wv * 1024);
    gload16((const char*)kvt + (size_t)bh * 8192 + (size_t)g1 * 16, (char*)KVs + 4096 + wv * 1024);
  }
  if (tid < 64) ks_lds[tid] = ksum[bh * 64 + tid];
  __syncthreads();

  // denominator: Q[r]·K_sum, 4-way split over d
  {
    const int r = tid & 63, qd = tid >> 6;
    float p = 0.f;
#pragma unroll
    for (int i = 0; i < 16; i++) p += (float)Qs[r * 64 + qd * 16 + i] * ks_lds[qd * 16 + i];
    dpart[qd][r] = p;
  }
  __syncthreads();
  if (tid < 64) {
    float den = dpart[0][tid] + dpart[1][tid] + dpart[2][tid] + dpart[3][tid];
    zr[tid] = 1.f / (den + 1e-6f);
  }
  __syncthreads();

  // Q(64x64) @ KV(64x64): wave wv owns rows wv*16..wv*16+15
  f32x4 acc[4] = {};
  const int fr = lane & 15;
  const int kg = (lane >> 4) * 8;
#pragma unroll
  for (int kh = 0; kh < 2; kh++) {
    f16x8 a = *(const f16x8*)&Qs[(wv * 16 + fr) * 64 + kh * 32 + kg];
#pragma unroll
    for (int n = 0; n < 4; n++) {
      f16x8 b8 = *(const f16x8*)&KVs[(n * 16 + fr) * 64 + kh * 32 + kg];
      acc[n] = __builtin_amdgcn_mfma_f32_16x16x32_f16(a, b8, acc[n], 0, 0, 0);
    }
  }

  const int rl = (lane >> 4) * 4, cl = lane & 15;
#pragma unroll
  for (int n = 0; n < 4; n++)
#pragma unroll
    for (int j = 0; j < 4; j++) {
      const int r = wv * 16 + rl + j;
      float v = acc[n][j] * zr[r];
      attn[(size_t)(m0 + r) * EE + h * DD + n * 16 + cl] = (_Float16)v;
    }
}

// ---------- launch ----------
extern "C" void kernel_launch(void* const* d_in, const int* in_sizes, int n_in,
                              void* d_out, int out_size, void* d_ws, size_t ws_size,
                              hipStream_t stream) {
  const float* x  = (const float*)d_in[0];
  const float* Wq = (const float*)d_in[1];
  const float* bq = (const float*)d_in[2];
  const float* Wk = (const float*)d_in[3];
  const float* bk = (const float*)d_in[4];
  const float* Wv = (const float*)d_in[5];
  const float* bv = (const float*)d_in[6];
  const float* Wo = (const float*)d_in[7];
  const float* bo = (const float*)d_in[8];
  float* out = (float*)d_out;

  char* ws = (char*)d_ws;
  size_t off = 0;
  auto alloc = [&](size_t bytes) -> char* {
    char* p = ws + off;
    off += (bytes + 255) & ~(size_t)255;
    return p;
  };
  _Float16* xh    = (_Float16*)alloc((size_t)MM * EE * 2);      // 32 MB
  _Float16* wqkv  = (_Float16*)alloc((size_t)3 * EE * EE * 2);  // 6 MB
  _Float16* woh   = (_Float16*)alloc((size_t)EE * EE * 2);      // 2 MB
  _Float16* Qh    = (_Float16*)alloc((size_t)MM * EE * 2);      // 32 MB
  _Float16* Kh    = (_Float16*)alloc((size_t)MM * EE * 2);      // 32 MB
  _Float16* Vh    = (_Float16*)alloc((size_t)MM * EE * 2);      // 32 MB
  float*    kvpart= (float*)alloc((size_t)16 * 64 * 4096 * 4);  // 16 MB
  float*    ksump = (float*)alloc((size_t)16 * 64 * 64 * 4);    // 256 KB
  _Float16* kvt   = (_Float16*)alloc((size_t)64 * 4096 * 2);    // 512 KB
  float*    ksum  = (float*)alloc((size_t)64 * 64 * 4);         // 16 KB
  _Float16* attn  = xh;  // xh is dead after the QKV GEMM; reuse (stream-ordered)

  (void)in_sizes; (void)n_in; (void)out_size; (void)ws_size;

  conv_all_kernel<<<2560, 256, 0, stream>>>(x, Wq, Wk, Wv, Wo, xh, wqkv, woh);
  // QKV projection: M=16384, N=3072 -> 64x24 = 1536 blocks (1536%8==0)
  gemm256<0><<<1536, 256, 0, stream>>>(xh, wqkv, bq, bk, bv, Qh, Kh, Vh, nullptr);
  kv_partial_kernel<<<dim3(64, 16), 256, 0, stream>>>(Kh, Vh, kvpart, ksump);
  kv_reduce_kernel<<<1040, 256, 0, stream>>>(kvpart, ksump, kvt, ksum);
  attn_kernel<<<dim3(64, 64), 256, 0, stream>>>(Qh, kvt, ksum, attn);
  // output projection: M=16384, N=1024 -> 64x8 = 512 blocks
  gemm256<1><<<512, 256, 0, stream>>>(attn, woh, bo, nullptr, nullptr,
                                      nullptr, nullptr, nullptr, out);
}

// Round 8
// 255.323 us; speedup vs baseline: 1.0384x; 1.0384x over previous
//
#include <hip/hip_runtime.h>
#include <math.h>

// ---------- problem constants ----------
#define BB 4
#define SS 4096
#define EE 1024
#define HH 16
#define DD 64
#define MM (BB*SS)          // 16384 rows

typedef _Float16 f16x8 __attribute__((ext_vector_type(8)));
typedef _Float16 f16x4 __attribute__((ext_vector_type(4)));
typedef float    f32x4 __attribute__((ext_vector_type(4)));

typedef __attribute__((address_space(3))) void lds_void;
typedef __attribute__((address_space(1))) void gm_void;

__device__ __forceinline__ void gload16(const void* g, void* l) {
  // async global->LDS, 16B per lane; LDS dest is wave-uniform base + lane*16
  __builtin_amdgcn_global_load_lds((gm_void*)g, (lds_void*)l, 16, 0, 0);
}

// ---------- fused conversion kernel (x -> f16, 4 weight mats -> f16) ----------
__global__ __launch_bounds__(256) void conv_all_kernel(const float* __restrict__ x,
                                                       const float* __restrict__ Wq,
                                                       const float* __restrict__ Wk,
                                                       const float* __restrict__ Wv,
                                                       const float* __restrict__ Wo,
                                                       _Float16* __restrict__ xh,
                                                       _Float16* __restrict__ wqkv,
                                                       _Float16* __restrict__ woh) {
  const int nx4 = (MM * EE) / 4;       // 4,194,304
  const int per = (EE * EE) / 4;       // 262,144
  const int ntot = nx4 + 4 * per;      // 5,242,880
  int i = blockIdx.x * blockDim.x + threadIdx.x;
  int stride = gridDim.x * blockDim.x;
  for (; i < ntot; i += stride) {
    const float* src;
    _Float16* dst;
    int off;
    if (i < nx4) {
      src = x; dst = xh; off = i;
    } else {
      int j = i - nx4;
      int seg = j / per; off = j - seg * per;
      src = (seg == 0) ? Wq : (seg == 1) ? Wk : (seg == 2) ? Wv : Wo;
      dst = (seg < 3) ? (wqkv + (size_t)seg * EE * EE) : woh;
    }
    f32x4 v = *(const f32x4*)&src[(size_t)off * 4];
    f16x4 h;
    h[0] = (_Float16)v[0]; h[1] = (_Float16)v[1];
    h[2] = (_Float16)v[2]; h[3] = (_Float16)v[3];
    *(f16x4*)&dst[(size_t)off * 4] = h;
  }
}

// ---------- 256x256 fp16 GEMM v7: faithful m201 8-phase, de-strangled ----------
// C[m][n] = sum_k A[m][k]*B[n][k], K = 1024 -> 16 K-tiles of BK=64.
// 512 threads = 8 waves (2M x 4N); per-wave output 128x64; acc[8][4] f32x4.
// LDS 128 KiB: A,B each 2dbuf x 2half x 128rows x 64k f16 (16KB half-tiles).
// Per tile: 4 phases; phase P reads A subtiles 2P,2P+1 (4 ds_read_b128; phase 0
// also reads all 8 B frags), stages one half-tile, raw s_barrier, setprio(1),
// 16 MFMA (C-quadrant x K=64), setprio(0), [phase 3: vmcnt(6)], raw s_barrier.
// vs R1 (800 TF): NO sched_barrier(0) wrappers (m141: order-pinning -> 510 TF),
// NO asm lgkmcnt(0) (C-level reads -> compiler emits partial lgkm waits, m97
// asm evidence). One sched_barrier per tile after the publish barrier.
// vmcnt ledger (per wave, 2 loads per half-tile stage): entering tile t:
// outstanding = {B0,B1,A0}(t+1) = 6. Stages: P0 A1(t+1), P1 B0(t+2),
// P2 B1(t+2), P3 A0(t+2) -> 14; vmcnt(6) retires 8 oldest = tile t+1 exactly.
// Swizzle: slot' = slot ^ (row&7) within 128B rows (2-way max = free, m136);
// stage source pre-swizzled per lane (both-sides-or-neither, rule 21).

#define VMW6 asm volatile("s_waitcnt vmcnt(6)" ::: "memory")
#define VMW0 asm volatile("s_waitcnt vmcnt(0)" ::: "memory")
#define NOP_ do {} while (0)

// stage half h (rows h*128..+127) of K-tile t into dbuf (t&1)
#define STA(t, h) do {                                                        \
    const char* s_ = AgL + (size_t)(h) * 262144 + (size_t)(t) * 128;          \
    char* d_ = LdsA + (((t) & 1) << 15) + ((h) << 14) + (wv << 10);           \
    gload16(s_, d_); gload16(s_ + 131072, d_ + 8192);                         \
  } while (0)
#define STB(t, h) do {                                                        \
    const char* s_ = BgL + (size_t)(h) * 262144 + (size_t)(t) * 128;          \
    char* d_ = LdsB + (((t) & 1) << 15) + ((h) << 14) + (wv << 10);           \
    gload16(s_, d_); gload16(s_ + 131072, d_ + 8192);                         \
  } while (0)

// swizzled fragment reads: subtile (16 rows x 64k = 2KB), row stride 128B,
// 16B slot index XOR'd with (row&7) (so0/so1 hold the per-lane result)
#define RA(bu, mf, ks) (*(const f16x8*)(LdsA + ((bu) << 15) + (wr << 14) +    \
    ((mf) << 11) + frb + ((ks) ? so1 : so0)))
#define RB(bu, nf, ks) (*(const f16x8*)(LdsB + ((bu) << 15) + ((wc >> 1) << 14) + \
    ((((wc & 1) << 2) | (nf)) << 11) + frb + ((ks) ? so1 : so0)))

#define PHASE(t, P, STG, VMC) do {                                            \
    const int bu = (t) & 1;                                                   \
    if ((P) == 0) {                                                           \
      _Pragma("unroll") for (int nf = 0; nf < 4; nf++) {                      \
        bfr[nf][0] = RB(bu, nf, 0); bfr[nf][1] = RB(bu, nf, 1);               \
      }                                                                       \
    }                                                                         \
    f16x8 a00 = RA(bu, 2 * (P), 0),     a01 = RA(bu, 2 * (P), 1);             \
    f16x8 a10 = RA(bu, 2 * (P) + 1, 0), a11 = RA(bu, 2 * (P) + 1, 1);         \
    STG;                                                                      \
    __builtin_amdgcn_s_barrier();                                             \
    __builtin_amdgcn_s_setprio(1);                                            \
    _Pragma("unroll") for (int nf = 0; nf < 4; nf++) {                        \
      acc[2*(P)][nf]   = __builtin_amdgcn_mfma_f32_16x16x32_f16(a00, bfr[nf][0], acc[2*(P)][nf], 0, 0, 0);   \
      acc[2*(P)][nf]   = __builtin_amdgcn_mfma_f32_16x16x32_f16(a01, bfr[nf][1], acc[2*(P)][nf], 0, 0, 0);   \
      acc[2*(P)+1][nf] = __builtin_amdgcn_mfma_f32_16x16x32_f16(a10, bfr[nf][0], acc[2*(P)+1][nf], 0, 0, 0); \
      acc[2*(P)+1][nf] = __builtin_amdgcn_mfma_f32_16x16x32_f16(a11, bfr[nf][1], acc[2*(P)+1][nf], 0, 0, 0); \
    }                                                                         \
    __builtin_amdgcn_s_setprio(0);                                            \
    VMC;                                                                      \
    __builtin_amdgcn_s_barrier();                                             \
  } while (0)

// one K-tile: stages A1(t+1), B0(t+2), B1(t+2), A0(t+2); vmcnt at phase 3
#define TILE(t, S1, S2, S3, S4, VMC) do {                                     \
    PHASE(t, 0, S1, NOP_);                                                    \
    PHASE(t, 1, S2, NOP_);                                                    \
    PHASE(t, 2, S3, NOP_);                                                    \
    PHASE(t, 3, S4, VMC);                                                     \
    __builtin_amdgcn_sched_barrier(0);                                        \
  } while (0)

template <int EPI>
__global__ __launch_bounds__(512, 2) void gemm256(const _Float16* __restrict__ A,
                                                  const _Float16* __restrict__ Bw,
                                                  const float* __restrict__ bias0,
                                                  const float* __restrict__ bias1,
                                                  const float* __restrict__ bias2,
                                                  _Float16* __restrict__ O0,
                                                  _Float16* __restrict__ O1,
                                                  _Float16* __restrict__ O2,
                                                  float* __restrict__ OF) {
  __shared__ __align__(16) char lds[131072];
  char* LdsA = lds;            // 2 dbuf x 2 half x 16KB
  char* LdsB = lds + 65536;

  const int tid  = threadIdx.x;
  const int lane = tid & 63;
  const int wv   = tid >> 6;           // 0..7
  const int wr   = wv >> 2;            // 0..1 -> rows [wr*128, +128)
  const int wc   = wv & 3;             // 0..3 -> cols [wc*64, +64)

  // T1: bijective XCD swizzle (gridDim.x % 8 == 0 for both instantiations)
  constexpr int NX = (EPI == 0) ? 12 : 4;
  const int q = (int)gridDim.x >> 3;
  const int bid = (int)blockIdx.x;
  const int sid = (bid & 7) * q + (bid >> 3);
  const int mbase = (sid / NX) << 8;
  const int nbase = (sid % NX) << 8;

  // read-side per-lane constants: row-in-subtile fr = lane&15, k-group kg = lane>>4
  const int fr  = lane & 15;
  const int kg  = lane >> 4;
  const int frb = fr << 7;                              // fr * 128
  const int so0 = ((kg ^ (fr & 7)) << 4);               // ks=0 slot (XOR-swizzled)
  const int so1 = (((4 | kg) ^ (fr & 7)) << 4);         // ks=1 slot
  // stage-side: lane covers row wv*8 + (lane>>3) (and +64), stored slot lane&7
  // holds global slot (lane&7) ^ (row&7) = (lane&7) ^ ((lane>>3)&7)
  const int srcsl = (((lane & 7) ^ (lane >> 3)) << 4);

  const char* AgL = (const char*)A +
      ((size_t)(mbase + (wv << 3) + (lane >> 3)) << 11) + srcsl;
  const char* BgL = (const char*)Bw +
      ((size_t)(nbase + (wv << 3) + (lane >> 3)) << 11) + srcsl;

  f32x4 acc[8][4] = {};
  f16x8 bfr[4][2];

  // prologue: A0(0) A1(0) B0(0) B1(0) B0(1) B1(1) A0(1); vmcnt(6) -> tile 0 resident
  STA(0, 0); STA(0, 1); STB(0, 0); STB(0, 1);
  STB(1, 0); STB(1, 1); STA(1, 0);
  VMW6;
  __builtin_amdgcn_s_barrier();
  __builtin_amdgcn_sched_barrier(0);

#pragma unroll 1
  for (int i = 0; i < 7; ++i) {        // tiles 0..13 steady state
    const int t = i << 1;
    TILE(t,     STA(t + 1, 1), STB(t + 2, 0), STB(t + 2, 1), STA(t + 2, 0), VMW6);
    TILE(t + 1, STA(t + 2, 1), STB(t + 3, 0), STB(t + 3, 1), STA(t + 3, 0), VMW6);
  }
  // tail: tile 14 stages only A1(15), drains; tile 15 pure compute
  TILE(14, STA(15, 1), NOP_, NOP_, NOP_, VMW0);
  TILE(15, NOP_, NOP_, NOP_, NOP_, NOP_);

  // epilogue: C/D layout col = lane&15, row = (lane>>4)*4 + j
  const int rl = (lane >> 4) << 2;
  const int cl = lane & 15;
  const int rb = mbase + (wr << 7);    // wave's 128-row block
  if (EPI == 0) {
    const int which = nbase >> 10;     // 0:Q 1:K 2:V (256-tile never straddles)
    const float* bias = (which == 0) ? bias0 : (which == 1) ? bias1 : bias2;
    _Float16* O = (which == 0) ? O0 : (which == 1) ? O1 : O2;
    const int cb = (nbase & 1023) + (wc << 6);
#pragma unroll
    for (int mf = 0; mf < 8; mf++) {
      const int gm = rb + (mf << 4) + rl;
#pragma unroll
      for (int nf = 0; nf < 4; nf++) {
        const int gc = cb + (nf << 4) + cl;
        const float bz = bias[gc];
#pragma unroll
        for (int j = 0; j < 4; j++) {
          float v = acc[mf][nf][j] + bz;
          if (which < 2) v = (v > 0.f) ? (v + 1.f) : expf(v);  // elu(v)+1
          O[(size_t)(gm + j) * EE + gc] = (_Float16)v;
        }
      }
    }
  } else {
    const int cb = nbase + (wc << 6);
#pragma unroll
    for (int mf = 0; mf < 8; mf++) {
      const int gm = rb + (mf << 4) + rl;
#pragma unroll
      for (int nf = 0; nf < 4; nf++) {
        const int gc = cb + (nf << 4) + cl;
        const float bz = bias0[gc];
#pragma unroll
        for (int j = 0; j < 4; j++)
          OF[(size_t)(gm + j) * EE + gc] = acc[mf][nf][j] + bz;
      }
    }
  }
}

#undef TILE
#undef PHASE
#undef RA
#undef RB
#undef STA
#undef STB

// ---------- stage 2: partial KV (K^T V) and partial K_sum, per (bh, s-chunk) ----------
__global__ __launch_bounds__(256) void kv_partial_kernel(const _Float16* __restrict__ Kh,
                                                         const _Float16* __restrict__ Vh,
                                                         float* __restrict__ kvpart,
                                                         float* __restrict__ ksump) {
  __shared__ __align__(16) _Float16 Ks[64 * 64];
  __shared__ __align__(16) _Float16 Vs[64 * 64];
  const int tid = threadIdx.x;
  const int wv = tid >> 6;
  const int bh = blockIdx.x;        // b*16 + h
  const int chunk = blockIdx.y;     // 16 chunks of 256 rows
  const int b = bh >> 4, h = bh & 15;
  const int td = tid >> 4, te = tid & 15;
  const int d0 = td * 4, e0 = te * 4;

  float kv[4][4] = {};
  float ks4[4] = {0.f, 0.f, 0.f, 0.f};

  for (int sub = 0; sub < 4; sub++) {
    const int s0 = chunk * 256 + sub * 64;
    __syncthreads();
    {
      const int g0 = tid, g1 = tid + 256;
      gload16((const char*)Kh + ((size_t)(b * SS + s0 + (g0 >> 3)) * EE + h * DD) * 2 + (g0 & 7) * 16,
              (char*)Ks + wv * 1024);
      gload16((const char*)Kh + ((size_t)(b * SS + s0 + (g1 >> 3)) * EE + h * DD) * 2 + (g1 & 7) * 16,
              (char*)Ks + 4096 + wv * 1024);
      gload16((const char*)Vh + ((size_t)(b * SS + s0 + (g0 >> 3)) * EE + h * DD) * 2 + (g0 & 7) * 16,
              (char*)Vs + wv * 1024);
      gload16((const char*)Vh + ((size_t)(b * SS + s0 + (g1 >> 3)) * EE + h * DD) * 2 + (g1 & 7) * 16,
              (char*)Vs + 4096 + wv * 1024);
    }
    __syncthreads();
#pragma unroll 8
    for (int s = 0; s < 64; s++) {
      f16x4 kk = *(const f16x4*)&Ks[s * 64 + d0];
      f16x4 vv = *(const f16x4*)&Vs[s * 64 + e0];
      float kf[4], vf[4];
#pragma unroll
      for (int i = 0; i < 4; i++) { kf[i] = (float)kk[i]; vf[i] = (float)vv[i]; }
#pragma unroll
      for (int i = 0; i < 4; i++)
#pragma unroll
        for (int j = 0; j < 4; j++) kv[i][j] += kf[i] * vf[j];
      if (te == 0) {
#pragma unroll
        for (int i = 0; i < 4; i++) ks4[i] += kf[i];
      }
    }
  }
  const size_t base = ((size_t)chunk * 64 + bh) * 4096;
#pragma unroll
  for (int i = 0; i < 4; i++)
#pragma unroll
    for (int j = 0; j < 4; j++) kvpart[base + (size_t)(d0 + i) * 64 + e0 + j] = kv[i][j];
  if (te == 0) {
#pragma unroll
    for (int i = 0; i < 4; i++) ksump[((size_t)chunk * 64 + bh) * 64 + d0 + i] = ks4[i];
  }
}

// ---------- stage 2b: reduce partials -> KV^T (fp16, [bh][e][d]) and K_sum (f32) ----------
__global__ __launch_bounds__(256) void kv_reduce_kernel(const float* __restrict__ kvpart,
                                                        const float* __restrict__ ksump,
                                                        _Float16* __restrict__ kvt,
                                                        float* __restrict__ ksum) {
  const int idx = blockIdx.x * 256 + threadIdx.x;
  if (blockIdx.x < 1024) {
    const int bh = idx >> 12;
    const int rem = idx & 4095;     // d*64 + e
    float s = 0.f;
#pragma unroll
    for (int c = 0; c < 16; c++) s += kvpart[((size_t)c * 64 + bh) * 4096 + rem];
    const int d = rem >> 6, e = rem & 63;
    kvt[(size_t)bh * 4096 + e * 64 + d] = (_Float16)s;
  } else {
    const int i2 = idx - 1024 * 256;  // 0..4095
    const int bh = i2 >> 6, d = i2 & 63;
    float s = 0.f;
#pragma unroll
    for (int c = 0; c < 16; c++) s += ksump[((size_t)c * 64 + bh) * 64 + d];
    ksum[i2] = s;
  }
}

// ---------- stage 3: attn[m][h*64+e] = Z * sum_d Q[m][d] * KV[d][e] ----------
__global__ __launch_bounds__(256) void attn_kernel(const _Float16* __restrict__ Qh,
                                                   const _Float16* __restrict__ kvt,
                                                   const float* __restrict__ ksum,
                                                   _Float16* __restrict__ attn) {
  __shared__ __align__(16) _Float16 Qs[64 * 64];
  __shared__ __align__(16) _Float16 KVs[64 * 64];
  __shared__ float ks_lds[64];
  __shared__ float dpart[4][64];
  __shared__ float zr[64];
  const int tid = threadIdx.x;
  const int lane = tid & 63;
  const int wv = tid >> 6;
  const int stile = blockIdx.x;     // 64 tiles of 64 rows
  const int bh = blockIdx.y;
  const int b = bh >> 4, h = bh & 15;
  const int m0 = b * SS + stile * 64;

  {
    const int g0 = tid, g1 = tid + 256;
    gload16((const char*)Qh + ((size_t)(m0 + (g0 >> 3)) * EE + h * DD) * 2 + (g0 & 7) * 16,
            (char*)Qs + wv * 1024);
    gload16((const char*)Qh + ((size_t)(m0 + (g1 >> 3)) * EE + h * DD) * 2 + (g1 & 7) * 16,
            (char*)Qs + 4096 + wv * 1024);
    gload16((const char*)kvt + (size_t)bh * 8192 + (size_t)g0 * 16, (char*)KVs + wv * 1024);
    gload16((const char*)kvt + (size_t)bh * 8192 + (size_t)g1 * 16, (char*)KVs + 4096 + wv * 1024);
  }
  if (tid < 64) ks_lds[tid] = ksum[bh * 64 + tid];
  __syncthreads();

  // denominator: Q[r]·K_sum, 4-way split over d
  {
    const int r = tid & 63, qd = tid >> 6;
    float p = 0.f;
#pragma unroll
    for (int i = 0; i < 16; i++) p += (float)Qs[r * 64 + qd * 16 + i] * ks_lds[qd * 16 + i];
    dpart[qd][r] = p;
  }
  __syncthreads();
  if (tid < 64) {
    float den = dpart[0][tid] + dpart[1][tid] + dpart[2][tid] + dpart[3][tid];
    zr[tid] = 1.f / (den + 1e-6f);
  }
  __syncthreads();

  // Q(64x64) @ KV(64x64): wave wv owns rows wv*16..wv*16+15
  f32x4 acc[4] = {};
  const int fr = lane & 15;
  const int kg = (lane >> 4) * 8;
#pragma unroll
  for (int kh = 0; kh < 2; kh++) {
    f16x8 a = *(const f16x8*)&Qs[(wv * 16 + fr) * 64 + kh * 32 + kg];
#pragma unroll
    for (int n = 0; n < 4; n++) {
      f16x8 b8 = *(const f16x8*)&KVs[(n * 16 + fr) * 64 + kh * 32 + kg];
      acc[n] = __builtin_amdgcn_mfma_f32_16x16x32_f16(a, b8, acc[n], 0, 0, 0);
    }
  }

  const int rl = (lane >> 4) * 4, cl = lane & 15;
#pragma unroll
  for (int n = 0; n < 4; n++)
#pragma unroll
    for (int j = 0; j < 4; j++) {
      const int r = wv * 16 + rl + j;
      float v = acc[n][j] * zr[r];
      attn[(size_t)(m0 + r) * EE + h * DD + n * 16 + cl] = (_Float16)v;
    }
}

// ---------- launch ----------
extern "C" void kernel_launch(void* const* d_in, const int* in_sizes, int n_in,
                              void* d_out, int out_size, void* d_ws, size_t ws_size,
                              hipStream_t stream) {
  const float* x  = (const float*)d_in[0];
  const float* Wq = (const float*)d_in[1];
  const float* bq = (const float*)d_in[2];
  const float* Wk = (const float*)d_in[3];
  const float* bk = (const float*)d_in[4];
  const float* Wv = (const float*)d_in[5];
  const float* bv = (const float*)d_in[6];
  const float* Wo = (const float*)d_in[7];
  const float* bo = (const float*)d_in[8];
  float* out = (float*)d_out;

  char* ws = (char*)d_ws;
  size_t off = 0;
  auto alloc = [&](size_t bytes) -> char* {
    char* p = ws + off;
    off += (bytes + 255) & ~(size_t)255;
    return p;
  };
  _Float16* xh    = (_Float16*)alloc((size_t)MM * EE * 2);      // 32 MB
  _Float16* wqkv  = (_Float16*)alloc((size_t)3 * EE * EE * 2);  // 6 MB
  _Float16* woh   = (_Float16*)alloc((size_t)EE * EE * 2);      // 2 MB
  _Float16* Qh    = (_Float16*)alloc((size_t)MM * EE * 2);      // 32 MB
  _Float16* Kh    = (_Float16*)alloc((size_t)MM * EE * 2);      // 32 MB
  _Float16* Vh    = (_Float16*)alloc((size_t)MM * EE * 2);      // 32 MB
  float*    kvpart= (float*)alloc((size_t)16 * 64 * 4096 * 4);  // 16 MB
  float*    ksump = (float*)alloc((size_t)16 * 64 * 64 * 4);    // 256 KB
  _Float16* kvt   = (_Float16*)alloc((size_t)64 * 4096 * 2);    // 512 KB
  float*    ksum  = (float*)alloc((size_t)64 * 64 * 4);         // 16 KB
  _Float16* attn  = xh;  // xh is dead after the QKV GEMM; reuse (stream-ordered)

  (void)in_sizes; (void)n_in; (void)out_size; (void)ws_size;

  conv_all_kernel<<<2560, 256, 0, stream>>>(x, Wq, Wk, Wv, Wo, xh, wqkv, woh);
  // QKV projection: M=16384, N=3072 -> 64x12 = 768 blocks (768%8==0)
  gemm256<0><<<768, 512, 0, stream>>>(xh, wqkv, bq, bk, bv, Qh, Kh, Vh, nullptr);
  kv_partial_kernel<<<dim3(64, 16), 256, 0, stream>>>(Kh, Vh, kvpart, ksump);
  kv_reduce_kernel<<<1040, 256, 0, stream>>>(kvpart, ksump, kvt, ksum);
  attn_kernel<<<dim3(64, 64), 256, 0, stream>>>(Qh, kvt, ksum, attn);
  // output projection: M=16384, N=1024 -> 64x4 = 256 blocks
  gemm256<1><<<256, 512, 0, stream>>>(attn, woh, bo, nullptr, nullptr,
                                      nullptr, nullptr, nullptr, out);
}